// Round 4
// baseline (9319.843 us; speedup 1.0000x reference)
//
#include <hip/hip_runtime.h>

typedef _Float16 f16;
typedef _Float16 f16x8 __attribute__((ext_vector_type(8)));
typedef _Float16 f16x4 __attribute__((ext_vector_type(4)));
typedef float f32x4 __attribute__((ext_vector_type(4)));

#define T_TOT 2048
#define BATCH 64
#define HID 256
#define G3 768
#define WS 32
#define NWIN 64
#define NRING 4

// flags (monotone single-writer counters), zero-initialized:
#define F_YPROG(lg)   (lg)                    // scan l: y windows produced
#define F_IPCONS(lg)  (24 + (lg))             // scan l: ip windows consumed
#define F_IPP(lg,q)   (48 + (lg)*4 + (q))     // worker q of layer l: ip produced
#define F_YC(lg,q)    (144 + (lg)*4 + (q))    // worker q of layer l+1: y consumed

__device__ __forceinline__ float fexp2(float x) { return __builtin_amdgcn_exp2f(x); }
__device__ __forceinline__ float frcp(float x) { return __builtin_amdgcn_rcpf(x); }
__device__ __forceinline__ float sigm(float x) {
    return frcp(1.0f + fexp2(-1.44269504088896f * x));
}
__device__ __forceinline__ float tanh_(float x) {
    return 1.0f - 2.0f * frcp(1.0f + fexp2(2.88539008177793f * x));
}

__device__ __forceinline__ int ld_acq(int* p) {
    return __hip_atomic_load(p, __ATOMIC_ACQUIRE, __HIP_MEMORY_SCOPE_AGENT);
}
__device__ __forceinline__ void st_rel(int* p, int v) {
    __hip_atomic_store(p, v, __ATOMIC_RELEASE, __HIP_MEMORY_SCOPE_AGENT);
}
__device__ __forceinline__ void wait_ge(int* f, int target, int tid) {
    if (tid == 0) {
        while (ld_acq(f) < target) __builtin_amdgcn_s_sleep(2);
    }
    __syncthreads();
}
__device__ __forceinline__ void wait4_ge(int* f, int target, int tid) {
    if (tid == 0) {
        #pragma unroll
        for (int q = 0; q < 4; ++q)
            while (ld_acq(f + q) < target) __builtin_amdgcn_s_sleep(2);
    }
    __syncthreads();
}
// barrier that drains ONLY LDS ops (not global stores/loads in flight)
__device__ __forceinline__ void bar_lgkm() {
    asm volatile("s_waitcnt lgkmcnt(0)\n\ts_barrier" ::: "memory");
}

__global__ void cvt_f16(const float* __restrict__ s, f16* __restrict__ d, int n) {
    int i = (blockIdx.x * 256 + threadIdx.x) * 4;
    if (i + 3 < n) {
        f32x4 v = *(const f32x4*)(s + i);
        f16x4 o = { (f16)v[0], (f16)v[1], (f16)v[2], (f16)v[3] };
        *(f16x4*)(d + i) = o;
    }
}

__global__ void bias_prep(const float* __restrict__ bi, const float* __restrict__ bh,
                          float* __restrict__ o) {
    int i = blockIdx.x * 256 + threadIdx.x;
    if (i < 6 * G3) {
        int g = i % G3;
        o[i] = bi[i] + (g < 512 ? bh[i] : 0.0f);
    }
}

// ---------------- scan role: one block = (layer l, batch group g of 16) ----------------
__device__ void scan_role(const f16* __restrict__ ipring, f16* __restrict__ yring,
                          const f16* __restrict__ whh, const float* __restrict__ bhh,
                          const float* __restrict__ h0, float* __restrict__ out,
                          int* flags, char* smem, int l, int g, int tid) {
    f16* hb = (f16*)smem;                      // double buffer [2][16*264]
    const int wv = tid >> 6, lane = tid & 63;
    const int quad = lane >> 4, b = lane & 15;
    const int gbase = 32 * wv + quad * 4;
    const int lg = l * 4 + g;

    // persistent W_hh fragments (A-operand; tile i -> gate i>>1, 16-row half i&1)
    f16x8 wf[6][8];
    #pragma unroll
    for (int i = 0; i < 6; ++i) {
        const f16* wp = whh + (long)l * G3 * HID
                      + ((i >> 1) * 256 + 32 * wv + (i & 1) * 16 + b) * 256 + quad * 8;
        #pragma unroll
        for (int kf = 0; kf < 8; ++kf)
            wf[i][kf] = *(const f16x8*)(wp + kf * 32);
    }
    f32x4 bhn[2];
    bhn[0] = *(const f32x4*)(bhh + l * G3 + 512 + gbase);
    bhn[1] = *(const f32x4*)(bhh + l * G3 + 512 + gbase + 16);

    {   // h0 -> buffer 0
        int bl = tid >> 5, c0 = (tid & 31) * 8;
        const float* hp = h0 + (long)(l * 64 + g * 16 + bl) * HID + c0;
        f32x4 v0 = *(const f32x4*)hp;
        f32x4 v1 = *(const f32x4*)(hp + 4);
        f16x8 h8 = { (f16)v0[0], (f16)v0[1], (f16)v0[2], (f16)v0[3],
                     (f16)v1[0], (f16)v1[1], (f16)v1[2], (f16)v1[3] };
        *(f16x8*)(&hb[bl * 264 + c0]) = h8;
    }
    __syncthreads();
    // this lane's h slice (it writes the same slice it needs as hprev)
    f16x4 hp_[2];
    hp_[0] = *(const f16x4*)(&hb[b * 264 + gbase]);
    hp_[1] = *(const f16x4*)(&hb[b * 264 + gbase + 16]);

    int cur = 0;
    for (int w = 0; w < NWIN; ++w) {
        if (l < 5 && w >= NRING)                // y ring back-pressure
            wait4_ge(flags + F_YC(lg, 0), w - NRING + 1, tid);
        wait4_ge(flags + F_IPP(lg, 0), w + 1, tid);
        const int slot = w & (NRING - 1);
        const f16* ipt = ipring + ((long)lg * NRING + slot) * 512 * G3
                       + (long)b * G3 + gbase;
        f16* yp = yring + (((long)lg * NRING + slot) * 512 + b) * HID + gbase;
        f16x4 pr[2], pz[2], pn[2];
        #pragma unroll
        for (int s = 0; s < 2; ++s) {           // prefetch t2=0
            pr[s] = *(const f16x4*)(ipt + s * 16);
            pz[s] = *(const f16x4*)(ipt + 256 + s * 16);
            pn[s] = *(const f16x4*)(ipt + 512 + s * 16);
        }
        for (int t2 = 0; t2 < WS; ++t2) {
            f32x4 acc[6];
            #pragma unroll
            for (int i = 0; i < 6; ++i) acc[i] = (f32x4){0.f, 0.f, 0.f, 0.f};
            #pragma unroll
            for (int kf = 0; kf < 8; ++kf) {
                f16x8 hf = *(const f16x8*)(&hb[cur * 4224 + b * 264 + kf * 32 + quad * 8]);
                #pragma unroll
                for (int i = 0; i < 6; ++i)
                    acc[i] = __builtin_amdgcn_mfma_f32_16x16x32_f16(wf[i][kf], hf, acc[i], 0, 0, 0);
            }
            #pragma unroll
            for (int s = 0; s < 2; ++s) {
                int gl = gbase + s * 16;
                f16x4 hnew;
                #pragma unroll
                for (int r = 0; r < 4; ++r) {
                    float rr = sigm(acc[s][r] + (float)pr[s][r]);
                    float zz = sigm(acc[2 + s][r] + (float)pz[s][r]);
                    float nn = tanh_((float)pn[s][r] + rr * (acc[4 + s][r] + bhn[s][r]));
                    float hv = nn + zz * ((float)hp_[s][r] - nn);
                    hnew[r] = (f16)hv;
                }
                hp_[s] = hnew;
                *(f16x4*)(&hb[(1 - cur) * 4224 + b * 264 + gl]) = hnew;
                if (l < 5) *(f16x4*)(yp + s * 16) = hnew;
            }
            if (t2 + 1 < WS) {                  // prefetch next step's ip
                const f16* ipn = ipt + 16 * G3;
                #pragma unroll
                for (int s = 0; s < 2; ++s) {
                    pr[s] = *(const f16x4*)(ipn + s * 16);
                    pz[s] = *(const f16x4*)(ipn + 256 + s * 16);
                    pn[s] = *(const f16x4*)(ipn + 512 + s * 16);
                }
            }
            bar_lgkm();                         // LDS-only drain; globals stay in flight
            cur ^= 1;
            ipt += 16 * G3;
            yp += 16 * HID;
        }
        __syncthreads();                        // full drain (vmcnt) before publish
        if (tid == 0) {
            st_rel(flags + F_IPCONS(lg), w + 1);
            if (l < 5) st_rel(flags + F_YPROG(lg), w + 1);
        }
    }
    {   // final h -> out (f32)
        int bl = tid >> 5, c0 = (tid & 31) * 8;
        f16x8 h8 = *(const f16x8*)(&hb[cur * 4224 + bl * 264 + c0]);
        float* op = out + (long)(l * 64 + g * 16 + bl) * HID + c0;
        f32x4 v0 = { (float)h8[0], (float)h8[1], (float)h8[2], (float)h8[3] };
        f32x4 v1 = { (float)h8[4], (float)h8[5], (float)h8[6], (float)h8[7] };
        *(f32x4*)op = v0;
        *(f32x4*)(op + 4) = v1;
    }
}

// -------- worker role: ip GEMM for (layer lay, group g), one 128-row m-tile (q) --------
template<int K>
__device__ void worker_role(const f16* __restrict__ src, bool is_x, int g,
                            const f16* __restrict__ Wl, const float* __restrict__ bias,
                            f16* __restrict__ dstb, int* flags,
                            int lay, int lg, int plg, int q,
                            char* smem, int tid) {
    f16* As = (f16*)smem;                      // [128][K]
    const int wv = tid >> 6, lane = tid & 63;
    const int quad = lane >> 4, l16 = lane & 15;
    const int mh = (wv & 1) * 64, nh = (wv >> 1) * 64;
    constexpr int CPR = K / 8;

    for (int w = 0; w < NWIN; ++w) {
        if (lay > 0) wait_ge(flags + F_YPROG(plg), w + 1, tid);
        if (w >= NRING) wait_ge(flags + F_IPCONS(lg), w - NRING + 1, tid);
        const int slot = w & (NRING - 1);
        f16* dst = dstb + (long)slot * 512 * G3;
        // stage A tile (rows q*128 .. q*128+128 of the window) with xor swizzle
        #pragma unroll
        for (int it = 0; it < (128 * CPR) / 512; ++it) {
            int idx = it * 512 + tid;
            int row = idx / CPR, c8 = idx % CPR;
            int wr = q * 128 + row;
            long soff;
            if (is_x) soff = ((long)(w * WS + (wr >> 4)) * 64 + g * 16 + (wr & 15)) * K + c8 * 8;
            else      soff = ((long)slot * 512 + wr) * K + c8 * 8;
            f16x8 v = *(const f16x8*)(src + soff);
            *(f16x8*)(&As[row * K + (c8 ^ (row & 7)) * 8]) = v;
        }
        __syncthreads();
        for (int nt = 0; nt < 3; ++nt) {
            f16x8 bfr[4][K / 32];
            #pragma unroll
            for (int ns = 0; ns < 4; ++ns) {
                int col = nt * 256 + nh + ns * 16 + l16;
                #pragma unroll
                for (int kf = 0; kf < K / 32; ++kf)
                    bfr[ns][kf] = *(const f16x8*)(Wl + (long)col * K + quad * 8 + kf * 32);
            }
            f32x4 acc[4][4];
            #pragma unroll
            for (int i = 0; i < 4; ++i)
                #pragma unroll
                for (int j = 0; j < 4; ++j) acc[i][j] = (f32x4){0.f, 0.f, 0.f, 0.f};
            #pragma unroll
            for (int kf = 0; kf < K / 32; ++kf) {
                f16x8 af[4];
                #pragma unroll
                for (int ms = 0; ms < 4; ++ms) {
                    int row = mh + ms * 16 + l16;
                    int c8 = (kf * 4 + quad) ^ (row & 7);
                    af[ms] = *(const f16x8*)(&As[row * K + c8 * 8]);
                }
                #pragma unroll
                for (int ms = 0; ms < 4; ++ms)
                    #pragma unroll
                    for (int ns = 0; ns < 4; ++ns)
                        acc[ms][ns] = __builtin_amdgcn_mfma_f32_16x16x32_f16(
                            af[ms], bfr[ns][kf], acc[ms][ns], 0, 0, 0);
            }
            #pragma unroll
            for (int ns = 0; ns < 4; ++ns) {
                int col = nt * 256 + nh + ns * 16 + l16;
                float bv = bias[col];
                #pragma unroll
                for (int ms = 0; ms < 4; ++ms) {
                    int wr0 = q * 128 + mh + ms * 16 + quad * 4;
                    #pragma unroll
                    for (int r = 0; r < 4; ++r)
                        dst[(long)(wr0 + r) * G3 + col] = (f16)(acc[ms][ns][r] + bv);
                }
            }
        }
        __syncthreads();                        // drains ip stores + protects As WAR
        if (tid == 0) {
            st_rel(flags + F_IPP(lg, q), w + 1);
            if (lay > 0) st_rel(flags + F_YC(plg, q), w + 1);
        }
    }
}

__global__ __launch_bounds__(512, 2) void gru_fused(
        const f16* __restrict__ xh, const f16* __restrict__ wih,
        const f16* __restrict__ whh, const float* __restrict__ biasc,
        const float* __restrict__ bhh, const float* __restrict__ h0,
        float* __restrict__ out, f16* __restrict__ yring, f16* __restrict__ ipring,
        int* flags) {
    __shared__ __align__(16) char smem[65536];
    const int bid = blockIdx.x, tid = threadIdx.x;
    if (bid < 24) {
        scan_role(ipring, yring, whh, bhh, h0, out, flags, smem, bid >> 2, bid & 3, tid);
    } else {
        int wid = bid - 24;                     // 96 workers: 6 layers x 4 groups x 4 quarters
        int lay = wid >> 4, g = (wid >> 2) & 3, q = wid & 3;
        int lg = lay * 4 + g;
        const float* bias = biasc + lay * G3;
        f16* dstb = ipring + (long)lg * NRING * 512 * G3;
        if (lay == 0) {
            worker_role<128>(xh, true, g, wih, bias, dstb, flags,
                             0, lg, 0, q, smem, tid);
        } else {
            int plg = (lay - 1) * 4 + g;
            const f16* Wl = wih + 768 * 128 + (long)(lay - 1) * G3 * HID;
            const f16* src = yring + (long)plg * NRING * 512 * HID;
            worker_role<256>(src, false, g, Wl, bias, dstb, flags,
                             lay, lg, plg, q, smem, tid);
        }
    }
}

extern "C" void kernel_launch(void* const* d_in, const int* in_sizes, int n_in,
                              void* d_out, int out_size, void* d_ws, size_t ws_size,
                              hipStream_t stream) {
    const float* x     = (const float*)d_in[0];   // [2048,64,128]
    const float* h0    = (const float*)d_in[1];   // [6,64,256]
    const float* w_ih0 = (const float*)d_in[2];   // [768,128]
    const float* w_ihr = (const float*)d_in[3];   // [5,768,256]
    const float* w_hh  = (const float*)d_in[4];   // [6,768,256]
    const float* b_ih  = (const float*)d_in[5];   // [6,768]
    const float* b_hh  = (const float*)d_in[6];   // [6,768]
    float* out = (float*)d_out;                   // [6,64,256]

    char* p = (char*)d_ws;
    f16* xh      = (f16*)p;   p += (long)T_TOT * BATCH * 128 * 2;        // 33.5 MB
    f16* wih     = (f16*)p;   p += (long)(768 * 128 + 5 * 768 * 256) * 2;
    f16* whh     = (f16*)p;   p += (long)6 * 768 * 256 * 2;
    float* biasc = (float*)p; p += (long)6 * G3 * 4;
    f16* yring   = (f16*)p;   p += (long)20 * NRING * 512 * HID * 2;     // 21 MB
    f16* ipring  = (f16*)p;   p += (long)24 * NRING * 512 * G3 * 2;      // 75.5 MB
    int* flags   = (int*)p;   p += 1024;

    hipMemsetAsync(flags, 0, 1024, stream);
    cvt_f16<<<16384, 256, 0, stream>>>(x, xh, T_TOT * BATCH * 128);
    cvt_f16<<<96, 256, 0, stream>>>(w_ih0, wih, 768 * 128);
    cvt_f16<<<960, 256, 0, stream>>>(w_ihr, wih + 768 * 128, 5 * 768 * 256);
    cvt_f16<<<1152, 256, 0, stream>>>(w_hh, whh, 6 * 768 * 256);
    bias_prep<<<18, 256, 0, stream>>>(b_ih, b_hh, biasc);

    gru_fused<<<120, 512, 0, stream>>>(xh, wih, whh, biasc, b_hh, h0, out,
                                       yring, ipring, flags);
}

// Round 5
// 8519.922 us; speedup vs baseline: 1.0939x; 1.0939x over previous
//
#include <hip/hip_runtime.h>

typedef _Float16 f16;
typedef _Float16 f16x8 __attribute__((ext_vector_type(8)));
typedef _Float16 f16x4 __attribute__((ext_vector_type(4)));
typedef float f32x4 __attribute__((ext_vector_type(4)));

#define T_TOT 2048
#define BATCH 64
#define HID 256
#define G3 768
#define WS 32
#define NWIN 64
#define NRING 4

// flags (monotone single-writer counters), zero-initialized:
#define F_YPROG(lg)   (lg)                    // scan l: y windows produced
#define F_IPCONS(lg)  (24 + (lg))             // scan l: ip windows consumed
#define F_IPP(lg,q)   (48 + (lg)*4 + (q))     // worker q of layer l: ip produced
#define F_YC(lg,q)    (144 + (lg)*4 + (q))    // worker q of layer l+1: y consumed

__device__ __forceinline__ float fexp2(float x) { return __builtin_amdgcn_exp2f(x); }
__device__ __forceinline__ float frcp(float x) { return __builtin_amdgcn_rcpf(x); }
__device__ __forceinline__ float sigm(float x) {
    return frcp(1.0f + fexp2(-1.44269504088896f * x));
}
__device__ __forceinline__ float tanh_(float x) {
    return 1.0f - 2.0f * frcp(1.0f + fexp2(2.88539008177793f * x));
}

__device__ __forceinline__ int ld_acq(int* p) {
    return __hip_atomic_load(p, __ATOMIC_ACQUIRE, __HIP_MEMORY_SCOPE_AGENT);
}
__device__ __forceinline__ void st_rel(int* p, int v) {
    __hip_atomic_store(p, v, __ATOMIC_RELEASE, __HIP_MEMORY_SCOPE_AGENT);
}
__device__ __forceinline__ void wait_ge(int* f, int target, int tid) {
    if (tid == 0) {
        while (ld_acq(f) < target) __builtin_amdgcn_s_sleep(2);
    }
    __syncthreads();
}
__device__ __forceinline__ void wait4_ge(int* f, int target, int tid) {
    if (tid == 0) {
        #pragma unroll
        for (int q = 0; q < 4; ++q)
            while (ld_acq(f + q) < target) __builtin_amdgcn_s_sleep(2);
    }
    __syncthreads();
}
// barrier draining ONLY LDS ops; global loads/stores stay in flight
__device__ __forceinline__ void bar_lgkm() {
    asm volatile("s_waitcnt lgkmcnt(0)\n\ts_barrier" ::: "memory");
}

__global__ void cvt_f16(const float* __restrict__ s, f16* __restrict__ d, int n) {
    int i = (blockIdx.x * 256 + threadIdx.x) * 4;
    if (i + 3 < n) {
        f32x4 v = *(const f32x4*)(s + i);
        f16x4 o = { (f16)v[0], (f16)v[1], (f16)v[2], (f16)v[3] };
        *(f16x4*)(d + i) = o;
    }
}

__global__ void bias_prep(const float* __restrict__ bi, const float* __restrict__ bh,
                          float* __restrict__ o) {
    int i = blockIdx.x * 256 + threadIdx.x;
    if (i < 6 * G3) {
        int g = i % G3;
        o[i] = bi[i] + (g < 512 ? bh[i] : 0.0f);
    }
}

// ---------------- scan role: one block = (layer l, batch group g of 16), 16 waves ------
// Wave wv owns gate-row tiles {r,z,n} x rows [16wv,16wv+16): wf[3][8] = 96 VGPRs/lane.
// Lane (quad,b) ends up with r,z,n MFMA results for the SAME h-rows 16wv+quad*4+[0,4),
// batch b -> gate nonlinearity entirely in registers.
__device__ void scan_role(const f16* __restrict__ ipring, f16* __restrict__ yring,
                          const f16* __restrict__ whh, const float* __restrict__ bhh,
                          const float* __restrict__ h0, float* __restrict__ out,
                          int* flags, char* smem, int l, int g, int tid) {
    f16* hb = (f16*)smem;                      // double buffer [2][16*264]
    const int wv = tid >> 6, lane = tid & 63;
    const int quad = lane >> 4, b = lane & 15;
    const int lg = l * 4 + g;
    const int R = 16 * wv + quad * 4;          // this lane's h-row base

    f16x8 wf[3][8];
    #pragma unroll
    for (int j = 0; j < 3; ++j) {
        const f16* wp = whh + (long)l * G3 * HID
                      + (long)(j * 256 + 16 * wv + b) * 256 + quad * 8;
        #pragma unroll
        for (int kf = 0; kf < 8; ++kf)
            wf[j][kf] = *(const f16x8*)(wp + kf * 32);
    }
    f32x4 bhn = *(const f32x4*)(bhh + l * G3 + 512 + R);

    {   // h0 -> buffer 0: wave wv loads batch wv
        const float* hp = h0 + (long)(l * 64 + g * 16 + wv) * HID + lane * 4;
        f32x4 v = *(const f32x4*)hp;
        f16x4 h4 = { (f16)v[0], (f16)v[1], (f16)v[2], (f16)v[3] };
        *(f16x4*)(&hb[wv * 264 + lane * 4]) = h4;
    }
    __syncthreads();
    f16x4 hp_ = *(const f16x4*)(&hb[b * 264 + R]);   // lane's own h slice

    int cur = 0;
    for (int w = 0; w < NWIN; ++w) {
        if (l < 5 && w >= NRING)
            wait4_ge(flags + F_YC(lg, 0), w - NRING + 1, tid);
        wait4_ge(flags + F_IPP(lg, 0), w + 1, tid);
        const int slot = w & (NRING - 1);
        const f16* ipt = ipring + ((long)lg * NRING + slot) * 512 * G3
                       + (long)b * G3 + R;
        f16* yp = yring + (((long)lg * NRING + slot) * 512 + b) * HID + R;
        f16x4 pr = *(const f16x4*)(ipt);
        f16x4 pz = *(const f16x4*)(ipt + 256);
        f16x4 pn = *(const f16x4*)(ipt + 512);
        for (int t2 = 0; t2 < WS; ++t2) {
            f32x4 a0 = {0.f,0.f,0.f,0.f}, a1 = a0, a2 = a0;
            #pragma unroll
            for (int kf = 0; kf < 8; ++kf) {
                f16x8 hf = *(const f16x8*)(&hb[cur * 4224 + b * 264 + kf * 32 + quad * 8]);
                a0 = __builtin_amdgcn_mfma_f32_16x16x32_f16(wf[0][kf], hf, a0, 0, 0, 0);
                a1 = __builtin_amdgcn_mfma_f32_16x16x32_f16(wf[1][kf], hf, a1, 0, 0, 0);
                a2 = __builtin_amdgcn_mfma_f32_16x16x32_f16(wf[2][kf], hf, a2, 0, 0, 0);
            }
            f16x4 hnew;
            #pragma unroll
            for (int r = 0; r < 4; ++r) {
                float rr = sigm(a0[r] + (float)pr[r]);
                float zz = sigm(a1[r] + (float)pz[r]);
                float nn = tanh_((float)pn[r] + rr * (a2[r] + bhn[r]));
                hnew[r] = (f16)(nn + zz * ((float)hp_[r] - nn));
            }
            hp_ = hnew;
            *(f16x4*)(&hb[(1 - cur) * 4224 + b * 264 + R]) = hnew;
            if (t2 + 1 < WS) {                  // prefetch BEFORE y store: loads ahead
                ipt += 16 * G3;                 // of stores in the vmcnt FIFO
                pr = *(const f16x4*)(ipt);
                pz = *(const f16x4*)(ipt + 256);
                pn = *(const f16x4*)(ipt + 512);
            }
            if (l < 5) *(f16x4*)yp = hnew;
            yp += 16 * HID;
            bar_lgkm();                         // LDS-only drain
            cur ^= 1;
        }
        __syncthreads();                        // full drain (vmcnt) before publish
        if (tid == 0) {
            st_rel(flags + F_IPCONS(lg), w + 1);
            if (l < 5) st_rel(flags + F_YPROG(lg), w + 1);
        }
    }
    {   // final h -> out (f32)
        f16x4 h4 = *(const f16x4*)(&hb[cur * 4224 + wv * 264 + lane * 4]);
        float* op = out + (long)(l * 64 + g * 16 + wv) * HID + lane * 4;
        f32x4 v = { (float)h4[0], (float)h4[1], (float)h4[2], (float)h4[3] };
        *(f32x4*)op = v;
    }
}

// -------- worker role: ip GEMM, 16 waves, one 128-row m-tile (q) per window ------------
// Lean registers: acc[2][4]=32, B-frag double buffer 32, per-kf JIT weight loads.
template<int K>
__device__ void worker_role(const f16* __restrict__ src, bool is_x, int g,
                            const f16* __restrict__ Wl, const float* __restrict__ bias,
                            f16* __restrict__ dstb, int* flags,
                            int lay, int lg, int plg, int q,
                            char* smem, int tid) {
    f16* As = (f16*)smem;                      // [128][K]
    const int wv = tid >> 6, lane = tid & 63;
    const int quad = lane >> 4, l16 = lane & 15;
    const int mi = wv & 3, ni = wv >> 2;
    constexpr int CPR = K / 8;

    for (int w = 0; w < NWIN; ++w) {
        if (lay > 0) wait_ge(flags + F_YPROG(plg), w + 1, tid);
        if (w >= NRING) wait_ge(flags + F_IPCONS(lg), w - NRING + 1, tid);
        const int slot = w & (NRING - 1);
        f16* dst = dstb + (long)slot * 512 * G3;
        #pragma unroll
        for (int it = 0; it < (128 * CPR) / 1024; ++it) {
            int idx = it * 1024 + tid;
            int row = idx / CPR, c8 = idx % CPR;
            int wr = q * 128 + row;
            long soff;
            if (is_x) soff = ((long)(w * WS + (wr >> 4)) * 64 + g * 16 + (wr & 15)) * K + c8 * 8;
            else      soff = ((long)slot * 512 + wr) * K + c8 * 8;
            f16x8 v = *(const f16x8*)(src + soff);
            *(f16x8*)(&As[row * K + (c8 ^ (row & 7)) * 8]) = v;
        }
        __syncthreads();
        for (int nt = 0; nt < 3; ++nt) {
            const int cbase = nt * 256 + ni * 64;
            f16x8 bc[4], bn[4];
            #pragma unroll
            for (int ns = 0; ns < 4; ++ns)
                bc[ns] = *(const f16x8*)(Wl + (long)(cbase + ns * 16 + l16) * K + quad * 8);
            f32x4 acc[2][4];
            #pragma unroll
            for (int i = 0; i < 2; ++i)
                #pragma unroll
                for (int j = 0; j < 4; ++j) acc[i][j] = (f32x4){0.f, 0.f, 0.f, 0.f};
            #pragma unroll
            for (int kf = 0; kf < K / 32; ++kf) {
                if (kf + 1 < K / 32) {
                    #pragma unroll
                    for (int ns = 0; ns < 4; ++ns)
                        bn[ns] = *(const f16x8*)(Wl + (long)(cbase + ns * 16 + l16) * K
                                                 + (kf + 1) * 32 + quad * 8);
                }
                f16x8 af[2];
                #pragma unroll
                for (int ms = 0; ms < 2; ++ms) {
                    int row = 32 * mi + 16 * ms + l16;
                    int c8 = (kf * 4 + quad) ^ (row & 7);
                    af[ms] = *(const f16x8*)(&As[row * K + c8 * 8]);
                }
                #pragma unroll
                for (int ms = 0; ms < 2; ++ms)
                    #pragma unroll
                    for (int ns = 0; ns < 4; ++ns)
                        acc[ms][ns] = __builtin_amdgcn_mfma_f32_16x16x32_f16(
                            af[ms], bc[ns], acc[ms][ns], 0, 0, 0);
                #pragma unroll
                for (int ns = 0; ns < 4; ++ns) bc[ns] = bn[ns];
            }
            #pragma unroll
            for (int ns = 0; ns < 4; ++ns) {
                int col = cbase + ns * 16 + l16;
                float bv = bias[col];
                #pragma unroll
                for (int ms = 0; ms < 2; ++ms) {
                    int m = q * 128 + 32 * mi + 16 * ms + quad * 4;
                    #pragma unroll
                    for (int r = 0; r < 4; ++r)
                        dst[(long)(m + r) * G3 + col] = (f16)(acc[ms][ns][r] + bv);
                }
            }
        }
        __syncthreads();                        // drains ip stores + protects As WAR
        if (tid == 0) {
            st_rel(flags + F_IPP(lg, q), w + 1);
            if (lay > 0) st_rel(flags + F_YC(plg, q), w + 1);
        }
    }
}

__global__ __launch_bounds__(1024, 4) void gru_fused(
        const f16* __restrict__ xh, const f16* __restrict__ wih,
        const f16* __restrict__ whh, const float* __restrict__ biasc,
        const float* __restrict__ bhh, const float* __restrict__ h0,
        float* __restrict__ out, f16* __restrict__ yring, f16* __restrict__ ipring,
        int* flags) {
    __shared__ __align__(16) char smem[65536];
    const int bid = blockIdx.x, tid = threadIdx.x;
    if (bid < 24) {
        scan_role(ipring, yring, whh, bhh, h0, out, flags, smem, bid >> 2, bid & 3, tid);
    } else {
        int wid = bid - 24;                     // 96 workers: layer x group x quarter
        int lay = wid >> 4, g = (wid >> 2) & 3, q = wid & 3;
        int lg = lay * 4 + g;
        const float* bias = biasc + lay * G3;
        f16* dstb = ipring + (long)lg * NRING * 512 * G3;
        if (lay == 0) {
            worker_role<128>(xh, true, g, wih, bias, dstb, flags,
                             0, lg, 0, q, smem, tid);
        } else {
            int plg = (lay - 1) * 4 + g;
            const f16* Wl = wih + 768 * 128 + (long)(lay - 1) * G3 * HID;
            const f16* src = yring + (long)plg * NRING * 512 * HID;
            worker_role<256>(src, false, g, Wl, bias, dstb, flags,
                             lay, lg, plg, q, smem, tid);
        }
    }
}

extern "C" void kernel_launch(void* const* d_in, const int* in_sizes, int n_in,
                              void* d_out, int out_size, void* d_ws, size_t ws_size,
                              hipStream_t stream) {
    const float* x     = (const float*)d_in[0];   // [2048,64,128]
    const float* h0    = (const float*)d_in[1];   // [6,64,256]
    const float* w_ih0 = (const float*)d_in[2];   // [768,128]
    const float* w_ihr = (const float*)d_in[3];   // [5,768,256]
    const float* w_hh  = (const float*)d_in[4];   // [6,768,256]
    const float* b_ih  = (const float*)d_in[5];   // [6,768]
    const float* b_hh  = (const float*)d_in[6];   // [6,768]
    float* out = (float*)d_out;                   // [6,64,256]

    char* p = (char*)d_ws;
    f16* xh      = (f16*)p;   p += (long)T_TOT * BATCH * 128 * 2;        // 33.5 MB
    f16* wih     = (f16*)p;   p += (long)(768 * 128 + 5 * 768 * 256) * 2;
    f16* whh     = (f16*)p;   p += (long)6 * 768 * 256 * 2;
    float* biasc = (float*)p; p += (long)6 * G3 * 4;
    f16* yring   = (f16*)p;   p += (long)20 * NRING * 512 * HID * 2;     // 21 MB
    f16* ipring  = (f16*)p;   p += (long)24 * NRING * 512 * G3 * 2;      // 75.5 MB
    int* flags   = (int*)p;   p += 1024;

    hipMemsetAsync(flags, 0, 1024, stream);
    cvt_f16<<<16384, 256, 0, stream>>>(x, xh, T_TOT * BATCH * 128);
    cvt_f16<<<96, 256, 0, stream>>>(w_ih0, wih, 768 * 128);
    cvt_f16<<<960, 256, 0, stream>>>(w_ihr, wih + 768 * 128, 5 * 768 * 256);
    cvt_f16<<<1152, 256, 0, stream>>>(w_hh, whh, 6 * 768 * 256);
    bias_prep<<<18, 256, 0, stream>>>(b_ih, b_hh, biasc);

    gru_fused<<<120, 1024, 0, stream>>>(xh, wih, whh, biasc, b_hh, h0, out,
                                        yring, ipring, flags);
}